// Round 3
// baseline (400.090 us; speedup 1.0000x reference)
//
#include <hip/hip_runtime.h>
#include <math.h>

#define TT 2048   // tokens
#define HH 1024   // hidden
#define EE 8      // experts
#define II 2048   // intermediate
#define N1 4096   // 2*II
#define ALPHA 1.702f
#define LIMIT 7.0f

typedef __attribute__((ext_vector_type(8))) short short8;
typedef __attribute__((ext_vector_type(4))) float floatx4;
typedef __attribute__((ext_vector_type(4))) unsigned int uintx4;

__device__ __forceinline__ short f2bf(float f) {
  union { float f; unsigned u; } v; v.f = f;
  unsigned r = (v.u + 0x7fffu + ((v.u >> 16) & 1u)) >> 16;
  return (short)r;
}
__device__ __forceinline__ float bf2f(unsigned short s) {
  union { unsigned u; float f; } v; v.u = ((unsigned)s) << 16;
  return v.f;
}
// 2x f32 -> packed bf16 (RNE) in one instruction
__device__ __forceinline__ unsigned cvt2(float lo, float hi) {
  unsigned r;
  asm("v_cvt_pk_bf16_f32 %0, %1, %2" : "=v"(r) : "v"(lo), "v"(hi));
  return r;
}

// LDS-only drain + barrier: does NOT drain vmcnt (unlike __syncthreads),
// so prefetched global loads stay in flight across the barrier.
#define LDS_BARRIER() asm volatile("s_waitcnt lgkmcnt(0)\ns_barrier" ::: "memory")

// ---------------- router: logits -> softmax -> top2 ----------------
__global__ __launch_bounds__(256) void router_kernel(
    const float* __restrict__ x, const float* __restrict__ rw,
    const float* __restrict__ rb, int* __restrict__ topk_idx,
    float* __restrict__ topk_w) {
  const int t = blockIdx.x;
  const float* xr = x + (size_t)t * HH;
  const int lane = threadIdx.x & 63;
  const int wave = threadIdx.x >> 6;
  float xv[16];
#pragma unroll
  for (int i = 0; i < 16; i++) xv[i] = xr[lane + i * 64];
  __shared__ float logits[EE];
#pragma unroll
  for (int ee = 0; ee < 2; ee++) {
    const int e = wave * 2 + ee;
    const float* wr = rw + (size_t)e * HH;
    float s = 0.f;
#pragma unroll
    for (int i = 0; i < 16; i++) s += xv[i] * wr[lane + i * 64];
#pragma unroll
    for (int off = 32; off > 0; off >>= 1) s += __shfl_down(s, off, 64);
    if (lane == 0) logits[e] = s + rb[e];
  }
  __syncthreads();
  if (threadIdx.x == 0) {
    float l[EE], sc[EE];
    float mx = -3.4e38f;
    for (int i = 0; i < EE; i++) { l[i] = logits[i]; mx = fmaxf(mx, l[i]); }
    float sum = 0.f;
    for (int i = 0; i < EE; i++) { sc[i] = expf(l[i] - mx); sum += sc[i]; }
    const float inv = 1.f / sum;
    int i0 = 0;
    for (int i = 1; i < EE; i++) if (sc[i] > sc[i0]) i0 = i;
    int i1 = (i0 == 0) ? 1 : 0;
    for (int i = 0; i < EE; i++) if (i != i0 && sc[i] > sc[i1]) i1 = i;
    topk_idx[t * 2 + 0] = i0;
    topk_idx[t * 2 + 1] = i1;
    topk_w[t * 2 + 0] = sc[i0] * inv;
    topk_w[t * 2 + 1] = sc[i1] * inv;
  }
}

// ---------------- token->expert compaction ----------------
__global__ void assign_kernel(const int* __restrict__ topk_idx,
                              int* __restrict__ counts, int* __restrict__ rows) {
  const int id = blockIdx.x * blockDim.x + threadIdx.x;
  if (id >= TT * 2) return;
  const int e = topk_idx[id];
  const int slot = atomicAdd(&counts[e], 1);
  rows[e * TT + slot] = id;  // entry = t*2 + k
}

// ---- GEMM1 fused: x(gather,f32->bf16) x gate_up[e] -> GLU act (bf16) ----
// Tile: 128 rows x 64 paired columns (gate col nc, up col nc+II).
// 8 waves (2M x 4N). LDS double-buffered, 1 barrier/k-step, 2 reg load sets
// (each global load has ~2 k-steps in flight before use; vmcnt never drains).
__global__ __launch_bounds__(512, 4) void gemm_gu_fused(
    const float* __restrict__ x, const float* __restrict__ gup,
    const float* __restrict__ gub, const int* __restrict__ counts,
    const int* __restrict__ rows, unsigned short* __restrict__ act) {
  const int e = blockIdx.z, mtile = blockIdx.y, ntile = blockIdx.x;
  const int count = counts[e];
  if (mtile * 128 >= count) return;
  const int* rl = rows + e * TT + mtile * 128;
  __shared__ short As[2][128][40];
  __shared__ short Bg[2][64][40];
  __shared__ short Bu[2][64][40];
  const int tid = threadIdx.x;
  const int lane = tid & 63, wave = tid >> 6;
  const int wm = (wave & 1) << 6, wn = (wave >> 1) << 4;  // 64 rows x 16 cols
  const int quad = lane >> 4, r16 = lane & 15;

  // A staging: thread -> (row, k-octet of 8 f32)
  const int arow = tid >> 2, akoct = tid & 3;
  const int cr = (mtile * 128 + arow < count) ? arow : (count - 1 - mtile * 128);
  const float* abase = x + (size_t)(rl[cr] >> 1) * HH + akoct * 8;

  // B staging: waves 0-3 stage gate cols, waves 4-7 stage up cols
  const int half = tid >> 8;
  const int bn = tid & 63, bko = (tid >> 6) & 3;
  const float* bbase = gup + (size_t)e * HH * N1 + (size_t)(bko * 8) * N1 +
                       (size_t)half * II + ntile * 64 + bn;
  short* bdst0 = half ? &Bu[0][bn][bko * 8] : &Bg[0][bn][bko * 8];
  short* bdst1 = half ? &Bu[1][bn][bko * 8] : &Bg[1][bn][bko * 8];

  floatx4 acc_g[4] = {{0.f,0.f,0.f,0.f},{0.f,0.f,0.f,0.f},{0.f,0.f,0.f,0.f},{0.f,0.f,0.f,0.f}};
  floatx4 acc_u[4] = {{0.f,0.f,0.f,0.f},{0.f,0.f,0.f,0.f},{0.f,0.f,0.f,0.f},{0.f,0.f,0.f,0.f}};

  const float* apA = abase;            // set A: tiles 0,2,4,...
  const float* apB = abase + 32;       // set B: tiles 1,3,5,...
  const float* bpA = bbase;
  const float* bpB = bbase + (size_t)32 * N1;

  float4 vaA0, vaA1, vaB0, vaB1;
  float vbA0, vbA1, vbA2, vbA3, vbA4, vbA5, vbA6, vbA7;
  float vbB0, vbB1, vbB2, vbB3, vbB4, vbB5, vbB6, vbB7;

#define GU_LOADA() do { \
  vaA0 = ((const float4*)apA)[0]; vaA1 = ((const float4*)apA)[1]; \
  vbA0 = bpA[0]; vbA1 = bpA[(size_t)1 * N1]; vbA2 = bpA[(size_t)2 * N1]; vbA3 = bpA[(size_t)3 * N1]; \
  vbA4 = bpA[(size_t)4 * N1]; vbA5 = bpA[(size_t)5 * N1]; vbA6 = bpA[(size_t)6 * N1]; vbA7 = bpA[(size_t)7 * N1]; \
  apA += 64; bpA += (size_t)64 * N1; } while (0)
#define GU_LOADB() do { \
  vaB0 = ((const float4*)apB)[0]; vaB1 = ((const float4*)apB)[1]; \
  vbB0 = bpB[0]; vbB1 = bpB[(size_t)1 * N1]; vbB2 = bpB[(size_t)2 * N1]; vbB3 = bpB[(size_t)3 * N1]; \
  vbB4 = bpB[(size_t)4 * N1]; vbB5 = bpB[(size_t)5 * N1]; vbB6 = bpB[(size_t)6 * N1]; vbB7 = bpB[(size_t)7 * N1]; \
  apB += 64; bpB += (size_t)64 * N1; } while (0)
#define GU_CVTW(buf, va0, va1, b0, b1, b2, b3, b4, b5, b6, b7) do { \
  uintx4 aw, bw; \
  aw[0] = cvt2(va0.x, va0.y); aw[1] = cvt2(va0.z, va0.w); \
  aw[2] = cvt2(va1.x, va1.y); aw[3] = cvt2(va1.z, va1.w); \
  bw[0] = cvt2(b0, b1); bw[1] = cvt2(b2, b3); \
  bw[2] = cvt2(b4, b5); bw[3] = cvt2(b6, b7); \
  *(uintx4*)&As[buf][arow][akoct * 8] = aw; \
  *(uintx4*)((buf) ? bdst1 : bdst0) = bw; } while (0)
#define GU_MMA(buf) do { \
  short8 af0 = *(const short8*)&As[buf][wm + 0 * 16 + r16][quad * 8]; \
  short8 af1 = *(const short8*)&As[buf][wm + 1 * 16 + r16][quad * 8]; \
  short8 af2 = *(const short8*)&As[buf][wm + 2 * 16 + r16][quad * 8]; \
  short8 af3 = *(const short8*)&As[buf][wm + 3 * 16 + r16][quad * 8]; \
  short8 bgf = *(const short8*)&Bg[buf][wn + r16][quad * 8]; \
  short8 buf_ = *(const short8*)&Bu[buf][wn + r16][quad * 8]; \
  __builtin_amdgcn_s_setprio(1); \
  acc_g[0] = __builtin_amdgcn_mfma_f32_16x16x32_bf16(af0, bgf, acc_g[0], 0, 0, 0); \
  acc_u[0] = __builtin_amdgcn_mfma_f32_16x16x32_bf16(af0, buf_, acc_u[0], 0, 0, 0); \
  acc_g[1] = __builtin_amdgcn_mfma_f32_16x16x32_bf16(af1, bgf, acc_g[1], 0, 0, 0); \
  acc_u[1] = __builtin_amdgcn_mfma_f32_16x16x32_bf16(af1, buf_, acc_u[1], 0, 0, 0); \
  acc_g[2] = __builtin_amdgcn_mfma_f32_16x16x32_bf16(af2, bgf, acc_g[2], 0, 0, 0); \
  acc_u[2] = __builtin_amdgcn_mfma_f32_16x16x32_bf16(af2, buf_, acc_u[2], 0, 0, 0); \
  acc_g[3] = __builtin_amdgcn_mfma_f32_16x16x32_bf16(af3, bgf, acc_g[3], 0, 0, 0); \
  acc_u[3] = __builtin_amdgcn_mfma_f32_16x16x32_bf16(af3, buf_, acc_u[3], 0, 0, 0); \
  __builtin_amdgcn_s_setprio(0); } while (0)

  GU_LOADA();                                           // tile 0 -> set A
  GU_LOADB();                                           // tile 1 -> set B
  GU_CVTW(0, vaA0, vaA1, vbA0, vbA1, vbA2, vbA3, vbA4, vbA5, vbA6, vbA7);  // tile 0
  GU_LOADA();                                           // tile 2 -> set A

  const int NT = HH / 32;  // 32
#pragma unroll 1
  for (int t = 0; t < NT; t += 2) {
    // even: read buf0 (tile t); cvt setB (tile t+1)->buf1; load setB <- t+3
    LDS_BARRIER();
    GU_CVTW(1, vaB0, vaB1, vbB0, vbB1, vbB2, vbB3, vbB4, vbB5, vbB6, vbB7);
    if (t + 3 < NT) GU_LOADB();
    GU_MMA(0);
    // odd: read buf1 (tile t+1); cvt setA (tile t+2)->buf0; load setA <- t+4
    LDS_BARRIER();
    if (t + 2 < NT) {
      GU_CVTW(0, vaA0, vaA1, vbA0, vbA1, vbA2, vbA3, vbA4, vbA5, vbA6, vbA7);
      if (t + 4 < NT) GU_LOADA();
    }
    GU_MMA(1);
  }

  // epilogue: bias + clamp + GLU, write act bf16
  const int nc = ntile * 64 + wn + r16;
  const float bg_bias = gub[e * N1 + nc];
  const float bu_bias = gub[e * N1 + II + nc];
#pragma unroll
  for (int i = 0; i < 4; i++) {
#pragma unroll
    for (int reg = 0; reg < 4; reg++) {
      const int rrow = wm + i * 16 + quad * 4 + reg;
      if (mtile * 128 + rrow < count) {
        const int ent = rl[rrow];
        float g = acc_g[i][reg] + bg_bias;
        float u = acc_u[i][reg] + bu_bias;
        g = fminf(g, LIMIT);
        u = fminf(fmaxf(u, -LIMIT), LIMIT);
        const float glu = g / (1.f + expf(-g * ALPHA));
        act[(size_t)ent * II + nc] = (unsigned short)f2bf((u + 1.f) * glu);
      }
    }
  }
#undef GU_LOADA
#undef GU_LOADB
#undef GU_CVTW
#undef GU_MMA
}

// ---------------- GEMM2: act (bf16) x down_proj[e] -> dout (f32), split-K=2 ----
// Same pipeline skeleton as gemm_gu_fused. blockIdx.z = e*2 + kchunk.
__global__ __launch_bounds__(512, 4) void gemm_down(
    const unsigned short* __restrict__ act, const float* __restrict__ dp,
    const float* __restrict__ db, const int* __restrict__ counts,
    const int* __restrict__ rows, float* __restrict__ dout0,
    float* __restrict__ dout1) {
  const int e = blockIdx.z >> 1, kc = blockIdx.z & 1;
  const int mtile = blockIdx.y, ntile = blockIdx.x;
  const int count = counts[e];
  if (mtile * 128 >= count) return;
  const int kb = kc * (II / 2);
  const int* rl = rows + e * TT + mtile * 128;
  __shared__ short As[2][128][40];
  __shared__ short Bs[2][128][40];
  const int tid = threadIdx.x;
  const int lane = tid & 63, wave = tid >> 6;
  const int wm = (wave & 1) << 6, wn = (wave >> 1) << 5;  // 64 rows x 32 cols
  const int quad = lane >> 4, r16 = lane & 15;

  const int arow = tid >> 2, akoct = tid & 3;
  const int cr = (mtile * 128 + arow < count) ? arow : (count - 1 - mtile * 128);
  const unsigned short* abase = act + (size_t)rl[cr] * II + kb + akoct * 8;

  const int bn = tid & 127, bko = tid >> 7;  // 0..3, 8 k's each
  const float* bbase = dp + (size_t)e * II * HH + (size_t)(kb + bko * 8) * HH +
                       ntile * 128 + bn;

  floatx4 acc[4][2] = {};

  const unsigned short* apA = abase;
  const unsigned short* apB = abase + 32;
  const float* bpA = bbase;
  const float* bpB = bbase + (size_t)32 * HH;

  short8 svA, svB;
  float vbA0, vbA1, vbA2, vbA3, vbA4, vbA5, vbA6, vbA7;
  float vbB0, vbB1, vbB2, vbB3, vbB4, vbB5, vbB6, vbB7;

#define DN_LOADA() do { \
  svA = *(const short8*)apA; \
  vbA0 = bpA[0]; vbA1 = bpA[(size_t)1 * HH]; vbA2 = bpA[(size_t)2 * HH]; vbA3 = bpA[(size_t)3 * HH]; \
  vbA4 = bpA[(size_t)4 * HH]; vbA5 = bpA[(size_t)5 * HH]; vbA6 = bpA[(size_t)6 * HH]; vbA7 = bpA[(size_t)7 * HH]; \
  apA += 64; bpA += (size_t)64 * HH; } while (0)
#define DN_LOADB() do { \
  svB = *(const short8*)apB; \
  vbB0 = bpB[0]; vbB1 = bpB[(size_t)1 * HH]; vbB2 = bpB[(size_t)2 * HH]; vbB3 = bpB[(size_t)3 * HH]; \
  vbB4 = bpB[(size_t)4 * HH]; vbB5 = bpB[(size_t)5 * HH]; vbB6 = bpB[(size_t)6 * HH]; vbB7 = bpB[(size_t)7 * HH]; \
  apB += 64; bpB += (size_t)64 * HH; } while (0)
#define DN_CVTW(buf, sv, b0, b1, b2, b3, b4, b5, b6, b7) do { \
  uintx4 bw; \
  bw[0] = cvt2(b0, b1); bw[1] = cvt2(b2, b3); \
  bw[2] = cvt2(b4, b5); bw[3] = cvt2(b6, b7); \
  *(short8*)&As[buf][arow][akoct * 8] = sv; \
  *(uintx4*)&Bs[buf][bn][bko * 8] = bw; } while (0)
#define DN_MMA(buf) do { \
  short8 af0 = *(const short8*)&As[buf][wm + 0 * 16 + r16][quad * 8]; \
  short8 af1 = *(const short8*)&As[buf][wm + 1 * 16 + r16][quad * 8]; \
  short8 af2 = *(const short8*)&As[buf][wm + 2 * 16 + r16][quad * 8]; \
  short8 af3 = *(const short8*)&As[buf][wm + 3 * 16 + r16][quad * 8]; \
  short8 bf0 = *(const short8*)&Bs[buf][wn + 0 * 16 + r16][quad * 8]; \
  short8 bf1 = *(const short8*)&Bs[buf][wn + 1 * 16 + r16][quad * 8]; \
  __builtin_amdgcn_s_setprio(1); \
  acc[0][0] = __builtin_amdgcn_mfma_f32_16x16x32_bf16(af0, bf0, acc[0][0], 0, 0, 0); \
  acc[0][1] = __builtin_amdgcn_mfma_f32_16x16x32_bf16(af0, bf1, acc[0][1], 0, 0, 0); \
  acc[1][0] = __builtin_amdgcn_mfma_f32_16x16x32_bf16(af1, bf0, acc[1][0], 0, 0, 0); \
  acc[1][1] = __builtin_amdgcn_mfma_f32_16x16x32_bf16(af1, bf1, acc[1][1], 0, 0, 0); \
  acc[2][0] = __builtin_amdgcn_mfma_f32_16x16x32_bf16(af2, bf0, acc[2][0], 0, 0, 0); \
  acc[2][1] = __builtin_amdgcn_mfma_f32_16x16x32_bf16(af2, bf1, acc[2][1], 0, 0, 0); \
  acc[3][0] = __builtin_amdgcn_mfma_f32_16x16x32_bf16(af3, bf0, acc[3][0], 0, 0, 0); \
  acc[3][1] = __builtin_amdgcn_mfma_f32_16x16x32_bf16(af3, bf1, acc[3][1], 0, 0, 0); \
  __builtin_amdgcn_s_setprio(0); } while (0)

  DN_LOADA();     // tile 0
  DN_LOADB();     // tile 1
  DN_CVTW(0, svA, vbA0, vbA1, vbA2, vbA3, vbA4, vbA5, vbA6, vbA7);
  DN_LOADA();     // tile 2

  const int NT = (II / 2) / 32;  // 32
#pragma unroll 1
  for (int t = 0; t < NT; t += 2) {
    LDS_BARRIER();
    DN_CVTW(1, svB, vbB0, vbB1, vbB2, vbB3, vbB4, vbB5, vbB6, vbB7);
    if (t + 3 < NT) DN_LOADB();
    DN_MMA(0);
    LDS_BARRIER();
    if (t + 2 < NT) {
      DN_CVTW(0, svA, vbA0, vbA1, vbA2, vbA3, vbA4, vbA5, vbA6, vbA7);
      if (t + 4 < NT) DN_LOADA();
    }
    DN_MMA(1);
  }

  float* dc = kc ? dout1 : dout0;
#pragma unroll
  for (int i = 0; i < 4; i++) {
#pragma unroll
    for (int reg = 0; reg < 4; reg++) {
      const int rrow = wm + i * 16 + quad * 4 + reg;
      if (mtile * 128 + rrow < count) {
        const int ent = rl[rrow];
        float* orow = dc + (size_t)ent * HH + ntile * 128;
#pragma unroll
        for (int j = 0; j < 2; j++) {
          const int c = wn + j * 16 + r16;
          float v = acc[i][j][reg];
          if (kc == 0) v += db[e * HH + ntile * 128 + c];
          orow[c] = v;
        }
      }
    }
  }
#undef DN_LOADA
#undef DN_LOADB
#undef DN_CVTW
#undef DN_MMA
}

// ---------------- combine: out = w0*(d0a+d1a) + w1*(d0b+d1b) ----------------
__global__ void combine_kernel(const float* __restrict__ d0,
                               const float* __restrict__ d1,
                               const float* __restrict__ tw,
                               float* __restrict__ out) {
  const int id = blockIdx.x * blockDim.x + threadIdx.x;
  const int t = id >> 8;            // H/4 = 256 float4 per token
  const int h = (id & 255) * 4;
  const float w0 = tw[t * 2], w1 = tw[t * 2 + 1];
  const size_t r0 = (size_t)(2 * t) * HH + h;
  const size_t r1 = (size_t)(2 * t + 1) * HH + h;
  const float4 a0 = *(const float4*)(d0 + r0);
  const float4 a1 = *(const float4*)(d1 + r0);
  const float4 b0 = *(const float4*)(d0 + r1);
  const float4 b1 = *(const float4*)(d1 + r1);
  float4 o;
  o.x = w0 * (a0.x + a1.x) + w1 * (b0.x + b1.x);
  o.y = w0 * (a0.y + a1.y) + w1 * (b0.y + b1.y);
  o.z = w0 * (a0.z + a1.z) + w1 * (b0.z + b1.z);
  o.w = w0 * (a0.w + a1.w) + w1 * (b0.w + b1.w);
  *(float4*)(out + (size_t)t * HH + h) = o;
}

extern "C" void kernel_launch(void* const* d_in, const int* in_sizes, int n_in,
                              void* d_out, int out_size, void* d_ws, size_t ws_size,
                              hipStream_t stream) {
  const float* x   = (const float*)d_in[0];
  const float* rw  = (const float*)d_in[1];
  const float* rb  = (const float*)d_in[2];
  const float* gup = (const float*)d_in[3];
  const float* gub = (const float*)d_in[4];
  const float* dp  = (const float*)d_in[5];
  const float* db  = (const float*)d_in[6];
  float* out = (float*)d_out;

  char* ws = (char*)d_ws;
  int*   topk_idx = (int*)(ws + 0);                       // 16 KB
  float* topk_w   = (float*)(ws + 16384);                 // 16 KB
  int*   counts   = (int*)(ws + 32768);                   // 256 B
  int*   rows     = (int*)(ws + 33024);                   // 64 KB
  unsigned short* act = (unsigned short*)(ws + 131072);               // 16.8 MB
  float* dout0 = (float*)(ws + 131072 + 16777216);                    // 16.8 MB
  float* dout1 = (float*)(ws + 131072 + 2 * 16777216);                // 16.8 MB

  router_kernel<<<TT, 256, 0, stream>>>(x, rw, rb, topk_idx, topk_w);
  hipMemsetAsync(counts, 0, 64, stream);
  assign_kernel<<<(TT * 2 + 255) / 256, 256, 0, stream>>>(topk_idx, counts, rows);
  gemm_gu_fused<<<dim3(II / 64, TT / 128, EE), 512, 0, stream>>>(x, gup, gub, counts, rows, act);
  gemm_down<<<dim3(HH / 128, TT / 128, EE * 2), 512, 0, stream>>>(act, dp, db, counts, rows, dout0, dout1);
  combine_kernel<<<(TT * HH / 4) / 256, 256, 0, stream>>>(dout0, dout1, topk_w, out);
}